// Round 20
// baseline (39.188 us; speedup 1.0000x reference)
//
#include <hip/hip_runtime.h>

#define NN 4096
#define FIN 256
#define FOUT 64
#define NH 4
#define CAP 128    // max edges/row; Binomial(4096,0.01) P(>127) ~ 1e-30
#define WROW 258   // padded shorts per ws row (516 B -> bank-spread writes)

typedef __attribute__((ext_vector_type(8))) short bf16x8;
typedef __attribute__((ext_vector_type(4))) float f32x4;

__device__ __forceinline__ unsigned short f2bf(float f) {   // RNE f32->bf16
    unsigned u = __float_as_uint(f);
    u = (u + 0x7fff + ((u >> 16) & 1)) >> 16;
    return (unsigned short)u;
}
__device__ __forceinline__ float bf2f(unsigned short s) {
    return __uint_as_float((unsigned)s << 16);
}
__device__ __forceinline__ int mbcnt64(unsigned long long m) {
    return __builtin_amdgcn_mbcnt_hi((unsigned)(m >> 32),
           __builtin_amdgcn_mbcnt_lo((unsigned)m, 0));
}

// ---------------------------------------------------------------------------
// K1: MFMA hprime (r18 verbatim). 512 blocks = (head, 32-node group);
// wave = 16 nodes x 32 outs; w staged transposed in LDS; B-granule = one
// ds_read_b128. Outputs bf16 hb + node-major sd.
// ---------------------------------------------------------------------------
__global__ __launch_bounds__(256) void gat_hprime(
    const float* __restrict__ h, const float* __restrict__ w,
    const float* __restrict__ a_src, const float* __restrict__ a_dst,
    unsigned short* __restrict__ hb, float* __restrict__ sd)
{
    const int b = blockIdx.x, t = threadIdx.x;
    const int head = b & 3, n0 = (b >> 2) * 32;
    const int wv = t >> 6, lane = t & 63;
    const int lrow = lane & 15, lk8 = lane >> 4;

    __shared__ __align__(16) unsigned short ws[64 * WROW];  // 33 KB
    __shared__ float sdbuf[2][2][16][2];

#pragma unroll
    for (int i = 0; i < 16; ++i) {
        const int k  = (t >> 4) + i * 16;
        const int o4 = (t & 15) * 4;
        const float4 v = *(const float4*)(w + ((size_t)head * FIN + k) * FOUT + o4);
        ws[(o4 + 0) * WROW + k] = f2bf(v.x);
        ws[(o4 + 1) * WROW + k] = f2bf(v.y);
        ws[(o4 + 2) * WROW + k] = f2bf(v.z);
        ws[(o4 + 3) * WROW + k] = f2bf(v.w);
    }

    const float* hrow = h + (size_t)(n0 + (wv >> 1) * 16 + lrow) * FIN + lk8 * 8;
    bf16x8 a[8];
#pragma unroll
    for (int ks = 0; ks < 8; ++ks) {
        const float4 v0 = *(const float4*)(hrow + ks * 32);
        const float4 v1 = *(const float4*)(hrow + ks * 32 + 4);
        union { bf16x8 v; unsigned short s[8]; } u;
        u.s[0] = f2bf(v0.x); u.s[1] = f2bf(v0.y);
        u.s[2] = f2bf(v0.z); u.s[3] = f2bf(v0.w);
        u.s[4] = f2bf(v1.x); u.s[5] = f2bf(v1.y);
        u.s[6] = f2bf(v1.z); u.s[7] = f2bf(v1.w);
        a[ks] = u.v;
    }
    __syncthreads();

    const int obase = (wv & 1) * 32;
    f32x4 acc[2] = {{0.f,0.f,0.f,0.f},{0.f,0.f,0.f,0.f}};
#pragma unroll
    for (int ks = 0; ks < 8; ++ks) {
#pragma unroll
        for (int nt = 0; nt < 2; ++nt) {
            const bf16x8 bf = *(const bf16x8*)
                &ws[(obase + nt * 16 + lrow) * WROW + ks * 32 + lk8 * 8];
            acc[nt] = __builtin_amdgcn_mfma_f32_16x16x32_bf16(a[ks], bf, acc[nt], 0, 0, 0);
        }
    }

    const int mbase = n0 + (wv >> 1) * 16 + lk8 * 4;
#pragma unroll
    for (int nt = 0; nt < 2; ++nt)
#pragma unroll
        for (int r = 0; r < 4; ++r)
            hb[((size_t)head * NN + mbase + r) * FOUT + obase + nt * 16 + lrow] =
                f2bf(acc[nt][r]);

    float as_nt[2], ad_nt[2];
#pragma unroll
    for (int nt = 0; nt < 2; ++nt) {
        as_nt[nt] = a_src[head * FOUT + obase + nt * 16 + lrow];
        ad_nt[nt] = a_dst[head * FOUT + obase + nt * 16 + lrow];
    }
    float psr[4] = {0.f,0.f,0.f,0.f}, pdr[4] = {0.f,0.f,0.f,0.f};
#pragma unroll
    for (int nt = 0; nt < 2; ++nt)
#pragma unroll
        for (int r = 0; r < 4; ++r) {
            psr[r] = fmaf(acc[nt][r], as_nt[nt], psr[r]);
            pdr[r] = fmaf(acc[nt][r], ad_nt[nt], pdr[r]);
        }
#pragma unroll
    for (int r = 0; r < 4; ++r)
#pragma unroll
        for (int off = 1; off <= 8; off <<= 1) {
            psr[r] += __shfl_xor(psr[r], off, 64);
            pdr[r] += __shfl_xor(pdr[r], off, 64);
        }
    if (lrow == 0)
#pragma unroll
        for (int r = 0; r < 4; ++r) {
            sdbuf[wv >> 1][wv & 1][lk8 * 4 + r][0] = psr[r];
            sdbuf[wv >> 1][wv & 1][lk8 * 4 + r][1] = pdr[r];
        }
    __syncthreads();
    if ((wv & 1) == 0 && lrow == 0) {
        const int p = wv >> 1;
#pragma unroll
        for (int r = 0; r < 4; ++r) {
            const int n = lk8 * 4 + r;
            const int node = n0 + p * 16 + n;
            sd[(size_t)node * 8 + head]     = sdbuf[p][0][n][0] + sdbuf[p][1][n][0];
            sd[(size_t)node * 8 + 4 + head] = sdbuf[p][0][n][1] + sdbuf[p][1][n][1];
        }
    }
}

// ---------------------------------------------------------------------------
// K2: BARRIER-FREE wave-per-row attn. 1024 blocks x 4 independent waves;
// wave wv owns row i = blockIdx*4+wv, with a private LDS slice. No
// __syncthreads anywhere: waves de-synchronize, so the CU's adj stream
// issues continuously instead of in block-lockstep bursts.
// Pipeline per wave: 16 int4 adj loads (2 halves) -> ballot-compact ->
// per-lane scores (p = lane, lane+64) + wave-shfl max/sum (no LDS ping-pong)
// -> packed float4 exp weights -> 4-edge x 4-head batched gather.
// ---------------------------------------------------------------------------
__global__ __launch_bounds__(256) void gat_attn(
    const int* __restrict__ adj, const unsigned short* __restrict__ hb,
    const float* __restrict__ sd, const float* __restrict__ bias,
    float* __restrict__ out)
{
    const int t = threadIdx.x, wv = t >> 6, lane = t & 63;
    const int i = blockIdx.x * 4 + wv;

    __shared__ int   idx_l[4][CAP];
    __shared__ float scpk[4][CAP][4];   // packed per-edge exp weights, 4 heads

    // ---- compaction: ballots, private LDS slice, no cross-wave coupling ----
    const int4* arow = (const int4*)(adj + (size_t)i * NN);
    int run = 0;
#pragma unroll
    for (int half = 0; half < 2; ++half) {
        int4 v[8];
#pragma unroll
        for (int it = 0; it < 8; ++it) v[it] = arow[(half * 8 + it) * 64 + lane];
#pragma unroll
        for (int it = 0; it < 8; ++it) {
            const unsigned long long b0 = __ballot(v[it].x != 0);
            const unsigned long long b1 = __ballot(v[it].y != 0);
            const unsigned long long b2 = __ballot(v[it].z != 0);
            const unsigned long long b3 = __ballot(v[it].w != 0);
            int p = run + mbcnt64(b0) + mbcnt64(b1) + mbcnt64(b2) + mbcnt64(b3);
            const int col0 = ((half * 8 + it) * 64 + lane) * 4;
            if (v[it].x) { if (p < CAP) idx_l[wv][p] = col0;     ++p; }
            if (v[it].y) { if (p < CAP) idx_l[wv][p] = col0 + 1; ++p; }
            if (v[it].z) { if (p < CAP) idx_l[wv][p] = col0 + 2; ++p; }
            if (v[it].w) { if (p < CAP) idx_l[wv][p] = col0 + 3; ++p; }
            run += __popcll(b0) + __popcll(b1) + __popcll(b2) + __popcll(b3);
        }
    }
    const int count = min(run, CAP);           // wave-uniform
    asm volatile("" ::: "memory");             // LDS fence (same-wave, in-order DS)

    // ---- scores: lane handles edges p=lane and p=lane+64 ----
    const float4 sv = *(const float4*)(sd + (size_t)i * 8);
    const bool actA = lane < count, actB = lane + 64 < count;
    const int jA = actA ? idx_l[wv][lane] : 0;
    const int jB = actB ? idx_l[wv][lane + 64] : 0;
    const float4 dvA = *(const float4*)(sd + (size_t)jA * 8 + 4);
    const float4 dvB = *(const float4*)(sd + (size_t)jB * 8 + 4);

    float sA[4], sB[4];
    {
        const float a0 = sv.x + dvA.x, a1 = sv.y + dvA.y,
                    a2 = sv.z + dvA.z, a3 = sv.w + dvA.w;
        const float b0 = sv.x + dvB.x, b1 = sv.y + dvB.y,
                    b2 = sv.z + dvB.z, b3 = sv.w + dvB.w;
        sA[0] = actA ? ((a0 >= 0.f) ? a0 : 0.2f * a0) : -3.4e38f;
        sA[1] = actA ? ((a1 >= 0.f) ? a1 : 0.2f * a1) : -3.4e38f;
        sA[2] = actA ? ((a2 >= 0.f) ? a2 : 0.2f * a2) : -3.4e38f;
        sA[3] = actA ? ((a3 >= 0.f) ? a3 : 0.2f * a3) : -3.4e38f;
        sB[0] = actB ? ((b0 >= 0.f) ? b0 : 0.2f * b0) : -3.4e38f;
        sB[1] = actB ? ((b1 >= 0.f) ? b1 : 0.2f * b1) : -3.4e38f;
        sB[2] = actB ? ((b2 >= 0.f) ? b2 : 0.2f * b2) : -3.4e38f;
        sB[3] = actB ? ((b3 >= 0.f) ? b3 : 0.2f * b3) : -3.4e38f;
    }

    float m[4], eA[4], eB[4], inv[4];
#pragma unroll
    for (int hh = 0; hh < 4; ++hh) {
        float mm = fmaxf(sA[hh], sB[hh]);
#pragma unroll
        for (int off = 32; off >= 1; off >>= 1)
            mm = fmaxf(mm, __shfl_xor(mm, off, 64));
        m[hh] = mm;
        eA[hh] = actA ? __expf(sA[hh] - mm) : 0.f;
        eB[hh] = actB ? __expf(sB[hh] - mm) : 0.f;
        float e = eA[hh] + eB[hh];
#pragma unroll
        for (int off = 32; off >= 1; off >>= 1)
            e += __shfl_xor(e, off, 64);
        inv[hh] = 1.f / e;
    }

    if (actA) *(float4*)&scpk[wv][lane][0]      = make_float4(eA[0], eA[1], eA[2], eA[3]);
    if (actB) *(float4*)&scpk[wv][lane + 64][0] = make_float4(eB[0], eB[1], eB[2], eB[3]);
    asm volatile("" ::: "memory");             // LDS fence before gather reads

    // ---- gather: 4 edges x 4 heads per batch (16 loads in flight) ----
    float acc[4] = {0.f, 0.f, 0.f, 0.f};
    const unsigned short* hpb = hb + lane;
    for (int p0 = 0; p0 < count; p0 += 4) {
        int jj[4]; float wts[4][4]; unsigned short hv[4][4];
#pragma unroll
        for (int k = 0; k < 4; ++k) {
            const int pp = p0 + k;
            const bool act = pp < count;
            jj[k] = act ? idx_l[wv][pp] : 0;
            const float4 wt = act ? *(const float4*)&scpk[wv][pp][0]
                                  : make_float4(0.f, 0.f, 0.f, 0.f);
            wts[k][0] = wt.x; wts[k][1] = wt.y; wts[k][2] = wt.z; wts[k][3] = wt.w;
        }
#pragma unroll
        for (int k = 0; k < 4; ++k)
#pragma unroll
            for (int hh = 0; hh < 4; ++hh)
                hv[k][hh] = hpb[((size_t)(hh * NN) + jj[k]) * FOUT];
#pragma unroll
        for (int k = 0; k < 4; ++k)
#pragma unroll
            for (int hh = 0; hh < 4; ++hh)
                acc[hh] = fmaf(wts[k][hh], bf2f(hv[k][hh]), acc[hh]);
    }

    const float bv = bias[lane];
#pragma unroll
    for (int hh = 0; hh < 4; ++hh)
        out[(size_t)i * (NH * FOUT) + hh * FOUT + lane] = acc[hh] * inv[hh] + bv;
}

extern "C" void kernel_launch(void* const* d_in, const int* in_sizes, int n_in,
                              void* d_out, int out_size, void* d_ws, size_t ws_size,
                              hipStream_t stream) {
    const float* h     = (const float*)d_in[0];
    const int*   adj   = (const int*)d_in[1];
    const float* w     = (const float*)d_in[2];
    const float* a_src = (const float*)d_in[3];
    const float* a_dst = (const float*)d_in[4];
    const float* bias  = (const float*)d_in[5];
    float* out = (float*)d_out;

    unsigned short* hb = (unsigned short*)d_ws;                 // 2 MB bf16 h'
    float* sd          = (float*)(hb + (size_t)NH * NN * FOUT); // NN*8 floats

    gat_hprime<<<512, 256, 0, stream>>>(h, w, a_src, a_dst, hb, sd);
    gat_attn<<<NN / 4, 256, 0, stream>>>(adj, hb, sd, bias, out);
}

// Round 21
// 34.646 us; speedup vs baseline: 1.1311x; 1.1311x over previous
//
#include <hip/hip_runtime.h>

#define NN 4096
#define FIN 256
#define FOUT 64
#define NH 4
#define CAP 128    // max edges/row; Binomial(4096,0.01) P(>127) ~ 1e-30
#define WROW 258   // padded shorts per ws row (516 B -> bank-spread writes)

typedef __attribute__((ext_vector_type(8))) short bf16x8;
typedef __attribute__((ext_vector_type(4))) float f32x4;

__device__ __forceinline__ unsigned short f2bf(float f) {   // RNE f32->bf16
    unsigned u = __float_as_uint(f);
    u = (u + 0x7fff + ((u >> 16) & 1)) >> 16;
    return (unsigned short)u;
}
__device__ __forceinline__ float bf2f(unsigned short s) {
    return __uint_as_float((unsigned)s << 16);
}
__device__ __forceinline__ int mbcnt64(unsigned long long m) {
    return __builtin_amdgcn_mbcnt_hi((unsigned)(m >> 32),
           __builtin_amdgcn_mbcnt_lo((unsigned)m, 0));
}

// ---------------------------------------------------------------------------
// K1: MFMA hprime (r18 verbatim). 512 blocks = (head, 32-node group);
// wave = 16 nodes x 32 outs; w staged transposed in LDS; B-granule = one
// ds_read_b128. Outputs bf16 hb [head][node][o] + node-major sd.
// ---------------------------------------------------------------------------
__global__ __launch_bounds__(256) void gat_hprime(
    const float* __restrict__ h, const float* __restrict__ w,
    const float* __restrict__ a_src, const float* __restrict__ a_dst,
    unsigned short* __restrict__ hb, float* __restrict__ sd)
{
    const int b = blockIdx.x, t = threadIdx.x;
    const int head = b & 3, n0 = (b >> 2) * 32;
    const int wv = t >> 6, lane = t & 63;
    const int lrow = lane & 15, lk8 = lane >> 4;

    __shared__ __align__(16) unsigned short ws[64 * WROW];  // 33 KB
    __shared__ float sdbuf[2][2][16][2];

#pragma unroll
    for (int i = 0; i < 16; ++i) {
        const int k  = (t >> 4) + i * 16;
        const int o4 = (t & 15) * 4;
        const float4 v = *(const float4*)(w + ((size_t)head * FIN + k) * FOUT + o4);
        ws[(o4 + 0) * WROW + k] = f2bf(v.x);
        ws[(o4 + 1) * WROW + k] = f2bf(v.y);
        ws[(o4 + 2) * WROW + k] = f2bf(v.z);
        ws[(o4 + 3) * WROW + k] = f2bf(v.w);
    }

    const float* hrow = h + (size_t)(n0 + (wv >> 1) * 16 + lrow) * FIN + lk8 * 8;
    bf16x8 a[8];
#pragma unroll
    for (int ks = 0; ks < 8; ++ks) {
        const float4 v0 = *(const float4*)(hrow + ks * 32);
        const float4 v1 = *(const float4*)(hrow + ks * 32 + 4);
        union { bf16x8 v; unsigned short s[8]; } u;
        u.s[0] = f2bf(v0.x); u.s[1] = f2bf(v0.y);
        u.s[2] = f2bf(v0.z); u.s[3] = f2bf(v0.w);
        u.s[4] = f2bf(v1.x); u.s[5] = f2bf(v1.y);
        u.s[6] = f2bf(v1.z); u.s[7] = f2bf(v1.w);
        a[ks] = u.v;
    }
    __syncthreads();

    const int obase = (wv & 1) * 32;
    f32x4 acc[2] = {{0.f,0.f,0.f,0.f},{0.f,0.f,0.f,0.f}};
#pragma unroll
    for (int ks = 0; ks < 8; ++ks) {
#pragma unroll
        for (int nt = 0; nt < 2; ++nt) {
            const bf16x8 bf = *(const bf16x8*)
                &ws[(obase + nt * 16 + lrow) * WROW + ks * 32 + lk8 * 8];
            acc[nt] = __builtin_amdgcn_mfma_f32_16x16x32_bf16(a[ks], bf, acc[nt], 0, 0, 0);
        }
    }

    const int mbase = n0 + (wv >> 1) * 16 + lk8 * 4;
#pragma unroll
    for (int nt = 0; nt < 2; ++nt)
#pragma unroll
        for (int r = 0; r < 4; ++r)
            hb[((size_t)head * NN + mbase + r) * FOUT + obase + nt * 16 + lrow] =
                f2bf(acc[nt][r]);

    float as_nt[2], ad_nt[2];
#pragma unroll
    for (int nt = 0; nt < 2; ++nt) {
        as_nt[nt] = a_src[head * FOUT + obase + nt * 16 + lrow];
        ad_nt[nt] = a_dst[head * FOUT + obase + nt * 16 + lrow];
    }
    float psr[4] = {0.f,0.f,0.f,0.f}, pdr[4] = {0.f,0.f,0.f,0.f};
#pragma unroll
    for (int nt = 0; nt < 2; ++nt)
#pragma unroll
        for (int r = 0; r < 4; ++r) {
            psr[r] = fmaf(acc[nt][r], as_nt[nt], psr[r]);
            pdr[r] = fmaf(acc[nt][r], ad_nt[nt], pdr[r]);
        }
#pragma unroll
    for (int r = 0; r < 4; ++r)
#pragma unroll
        for (int off = 1; off <= 8; off <<= 1) {
            psr[r] += __shfl_xor(psr[r], off, 64);
            pdr[r] += __shfl_xor(pdr[r], off, 64);
        }
    if (lrow == 0)
#pragma unroll
        for (int r = 0; r < 4; ++r) {
            sdbuf[wv >> 1][wv & 1][lk8 * 4 + r][0] = psr[r];
            sdbuf[wv >> 1][wv & 1][lk8 * 4 + r][1] = pdr[r];
        }
    __syncthreads();
    if ((wv & 1) == 0 && lrow == 0) {
        const int p = wv >> 1;
#pragma unroll
        for (int r = 0; r < 4; ++r) {
            const int n = lk8 * 4 + r;
            const int node = n0 + p * 16 + n;
            sd[(size_t)node * 8 + head]     = sdbuf[p][0][n][0] + sdbuf[p][1][n][0];
            sd[(size_t)node * 8 + 4 + head] = sdbuf[p][0][n][1] + sdbuf[p][1][n][1];
        }
    }
}

// ---------------------------------------------------------------------------
// K2: fused scan+attn, r16 structure (4096 blocks, 32 waves/CU) with a
// restructured gather: lane = (head = lane>>4, o-quad = lane&15); one
// dwordx2 per edge covers all 4 heads x 4 outs; edges split p%4 across
// waves (~11 loads/wave vs 168 before); partials combined via LDS.
// ---------------------------------------------------------------------------
__global__ __launch_bounds__(256) void gat_attn(
    const int* __restrict__ adj, const unsigned short* __restrict__ hb,
    const float* __restrict__ sd, const float* __restrict__ bias,
    float* __restrict__ out)
{
    const int i = blockIdx.x, t = threadIdx.x, wv = t >> 6, lane = t & 63;

    __shared__ int   idx_l[CAP];
    __shared__ float sc[NH][CAP];
    __shared__ int   ccnt[16];
    __shared__ float inv_sum[NH];
    __shared__ float accbuf[4][64][4];   // 4 KB: per-wave gather partials

    // Phase A: issue my 4 int4 loads of the row back-to-back
    const int4* arow = (const int4*)(adj + (size_t)i * NN);
    int4 a[4];
#pragma unroll
    for (int it = 0; it < 4; ++it) a[it] = arow[wv * 256 + it * 64 + lane];

    // Phase B: ballots -> within-chunk offset + per-chunk count
    int myoff[4];
#pragma unroll
    for (int it = 0; it < 4; ++it) {
        const unsigned long long b0 = __ballot(a[it].x != 0);
        const unsigned long long b1 = __ballot(a[it].y != 0);
        const unsigned long long b2 = __ballot(a[it].z != 0);
        const unsigned long long b3 = __ballot(a[it].w != 0);
        myoff[it] = mbcnt64(b0) + mbcnt64(b1) + mbcnt64(b2) + mbcnt64(b3);
        if (lane == 0)
            ccnt[wv * 4 + it] = __popcll(b0) + __popcll(b1) +
                                __popcll(b2) + __popcll(b3);
    }
    __syncthreads();

    // chunk-prefix (16 chunks) -> deterministic layout
    int cb[4];
    int s = 0;
#pragma unroll
    for (int k = 0; k < 16; ++k) {
        if ((k >> 2) == wv) cb[k & 3] = s;
        s += ccnt[k];
    }
    const int count = min(s, CAP);

    // Phase C: scatter edge columns into LDS
#pragma unroll
    for (int it = 0; it < 4; ++it) {
        int p = cb[it] + myoff[it];
        const int col0 = (wv * 256 + it * 64 + lane) * 4;
        if (a[it].x) { if (p < CAP) idx_l[p] = col0;     ++p; }
        if (a[it].y) { if (p < CAP) idx_l[p] = col0 + 1; ++p; }
        if (a[it].z) { if (p < CAP) idx_l[p] = col0 + 2; ++p; }
        if (a[it].w) { if (p < CAP) idx_l[p] = col0 + 3; ++p; }
    }
    __syncthreads();

    // scores: one float4 pair per edge covers all 4 heads
    if (t < count) {
        const int j = idx_l[t];
        const float4 sv = *(const float4*)(sd + (size_t)i * 8);       // src, 4 heads
        const float4 dv = *(const float4*)(sd + (size_t)j * 8 + 4);   // dst, 4 heads
        const float s0 = sv.x + dv.x, s1 = sv.y + dv.y;
        const float s2 = sv.z + dv.z, s3 = sv.w + dv.w;
        sc[0][t] = (s0 >= 0.f) ? s0 : 0.2f * s0;
        sc[1][t] = (s1 >= 0.f) ? s1 : 0.2f * s1;
        sc[2][t] = (s2 >= 0.f) ? s2 : 0.2f * s2;
        sc[3][t] = (s3 >= 0.f) ? s3 : 0.2f * s3;
    }
    __syncthreads();

    // per-head softmax (wave = head)
    {
        float m = -3.4e38f;
        for (int p = lane; p < count; p += 64) m = fmaxf(m, sc[wv][p]);
#pragma unroll
        for (int off = 32; off >= 1; off >>= 1) m = fmaxf(m, __shfl_xor(m, off, 64));
        float e = 0.f;
        for (int p = lane; p < count; p += 64) {
            const float v = __expf(sc[wv][p] - m);
            sc[wv][p] = v;
            e += v;
        }
#pragma unroll
        for (int off = 32; off >= 1; off >>= 1) e += __shfl_xor(e, off, 64);
        if (lane == 0) inv_sum[wv] = 1.f / e;
    }
    __syncthreads();

    // gather v2: lane = (hh = lane>>4, og = lane&15); wave wv takes p%4==wv.
    // One dwordx2 per edge: 4 consecutive bf16 = outputs og*4..og*4+3 of head hh.
    const int hh = lane >> 4, og = lane & 15;
    const unsigned short* hpb = hb + (size_t)hh * NN * FOUT + og * 4;
    float4 accv = make_float4(0.f, 0.f, 0.f, 0.f);
    for (int p0 = wv; p0 < count; p0 += 16) {     // 4 edges/iter, stride 4
        int jj[4]; float ee[4]; ushort4 hv[4];
#pragma unroll
        for (int k = 0; k < 4; ++k) {
            const int pp = p0 + k * 4;
            const bool act = pp < count;
            jj[k] = act ? idx_l[pp] : 0;
            ee[k] = act ? sc[hh][pp] : 0.f;       // LDS broadcast in 16-lane group
        }
#pragma unroll
        for (int k = 0; k < 4; ++k)
            hv[k] = *(const ushort4*)(hpb + (size_t)jj[k] * FOUT);
#pragma unroll
        for (int k = 0; k < 4; ++k) {
            accv.x = fmaf(ee[k], bf2f(hv[k].x), accv.x);
            accv.y = fmaf(ee[k], bf2f(hv[k].y), accv.y);
            accv.z = fmaf(ee[k], bf2f(hv[k].z), accv.z);
            accv.w = fmaf(ee[k], bf2f(hv[k].w), accv.w);
        }
    }
    *(float4*)&accbuf[wv][lane][0] = accv;
    __syncthreads();

    // combine the 4 wave-partials; wave 0 writes coalesced float4 outputs
    if (wv == 0) {
        float4 r0 = *(const float4*)&accbuf[0][lane][0];
        const float4 r1 = *(const float4*)&accbuf[1][lane][0];
        const float4 r2 = *(const float4*)&accbuf[2][lane][0];
        const float4 r3 = *(const float4*)&accbuf[3][lane][0];
        r0.x += r1.x + r2.x + r3.x;
        r0.y += r1.y + r2.y + r3.y;
        r0.z += r1.z + r2.z + r3.z;
        r0.w += r1.w + r2.w + r3.w;
        const float is = inv_sum[hh];
        const float4 bv = *(const float4*)(bias + og * 4);
        float4 o;
        o.x = r0.x * is + bv.x;
        o.y = r0.y * is + bv.y;
        o.z = r0.z * is + bv.z;
        o.w = r0.w * is + bv.w;
        *(float4*)(out + (size_t)i * (NH * FOUT) + hh * FOUT + og * 4) = o;
    }
}

extern "C" void kernel_launch(void* const* d_in, const int* in_sizes, int n_in,
                              void* d_out, int out_size, void* d_ws, size_t ws_size,
                              hipStream_t stream) {
    const float* h     = (const float*)d_in[0];
    const int*   adj   = (const int*)d_in[1];
    const float* w     = (const float*)d_in[2];
    const float* a_src = (const float*)d_in[3];
    const float* a_dst = (const float*)d_in[4];
    const float* bias  = (const float*)d_in[5];
    float* out = (float*)d_out;

    unsigned short* hb = (unsigned short*)d_ws;                 // 2 MB bf16 h'
    float* sd          = (float*)(hb + (size_t)NH * NN * FOUT); // NN*8 floats

    gat_hprime<<<512, 256, 0, stream>>>(h, w, a_src, a_dst, hb, sd);
    gat_attn<<<NN, 256, 0, stream>>>(adj, hb, sd, bias, out);
}